// Round 5
// baseline (580.122 us; speedup 1.0000x reference)
//
#include <hip/hip_runtime.h>
#include <hip/hip_bf16.h>
#include <cstdint>

// ---------------------------------------------------------------------------
// Gemma4 MoE FFN. N=4096 tokens, H=1024, ID=4096, IM=512, E=8, top-2.
// Round 5: 2-phase pipelined (stage-early) GEMMs, bf16 split-K partials
// (no atomics), expert-up BN=64 for occupancy, XOR-swizzled LDS (conflict-free).
// ---------------------------------------------------------------------------

typedef __attribute__((ext_vector_type(8))) short short8;
typedef __attribute__((ext_vector_type(4))) float floatx4;
typedef const void __attribute__((address_space(1)))* gptr_t;
typedef void __attribute__((address_space(3)))* sptr_t;

#define BF16 __hip_bfloat16

__device__ __forceinline__ float gelu_tanh(float x) {
  float x3 = x * x * x;
  float t = tanhf(0.7978845608028654f * (x + 0.044715f * x3));
  return 0.5f * x * (1.f + t);
}

// ---------------------------------------------------------------------------
// BK=64 tile [ROWS][64 bf16], 8 granules (16B) per row. LDS slot g holds
// source granule g ^ (row&7)  -> ds_read_b128 column reads hit all 8 quads.
// (measured round 4: SQ_LDS_BANK_CONFLICT -> 0)
// ---------------------------------------------------------------------------
template <int ROWS>
__device__ __forceinline__ void stage64t(const BF16* __restrict__ g, BF16* lds,
                                         int ldg, int wave, int lane) {
  const int rsub = lane >> 3;  // 0..7
  const int gcol = lane & 7;   // 0..7
#pragma unroll
  for (int j = 0; j < ROWS / 32; ++j) {
    int row = wave * (ROWS / 4) + j * 8 + rsub;
    const BF16* src = g + (size_t)row * ldg + ((gcol ^ rsub) * 8);
    BF16* dst = lds + (wave * (ROWS / 4) + j * 8) * 64;  // wave-uniform base
    __builtin_amdgcn_global_load_lds((gptr_t)src, (sptr_t)dst, 16, 0, 0);
  }
}

__device__ __forceinline__ short8 frag64(const BF16* lds, int fr, int kh, int lane) {
  int gk = kh * 4 + (lane >> 4);
  return *(const short8*)&lds[fr * 64 + ((gk ^ (fr & 7)) * 8)];
}

// ---------------------------------------------------------------------------
// BK=32 tile [128][32], 4 granules per row. Slot g holds source granule
// g ^ ((row>>1)&3): rows 0..7 cover all 8 bank-quads (16*(r&1)+4*g'), rows
// 8..15 repeat -> 2-way (free).
// ---------------------------------------------------------------------------
__device__ __forceinline__ void stage32(const BF16* __restrict__ g, BF16* lds,
                                        int ldg, int wave, int lane) {
  const int g4 = (lane & 3) ^ ((lane >> 3) & 3);
#pragma unroll
  for (int j = 0; j < 2; ++j) {
    int row = wave * 32 + j * 16 + (lane >> 2);
    const BF16* src = g + (size_t)row * ldg + g4 * 8;
    BF16* dst = lds + (wave * 32 + j * 16) * 32;
    __builtin_amdgcn_global_load_lds((gptr_t)src, (sptr_t)dst, 16, 0, 0);
  }
}

__device__ __forceinline__ short8 frag32(const BF16* lds, int fr, int lane) {
  int gk = lane >> 4;
  return *(const short8*)&lds[fr * 32 + ((gk ^ ((fr >> 1) & 3)) * 8)];
}

// ---------------------------------------------------------------------------
// Dense dual up-GEMM: HBUF = gelu(x@Wg)*(x@Wu). 128x128, BK=32, 2-phase dbuf.
// ---------------------------------------------------------------------------
__launch_bounds__(256, 2)
__global__ void gemm_up_dense(const BF16* __restrict__ A, const BF16* __restrict__ Bg,
                              const BF16* __restrict__ Bu, BF16* __restrict__ out) {
  constexpr int K = 1024, NT = K / 32;
  __shared__ __align__(16) BF16 la[2][128 * 32];
  __shared__ __align__(16) BF16 lg[2][128 * 32];
  __shared__ __align__(16) BF16 lu[2][128 * 32];
  const int lane = threadIdx.x & 63, wave = threadIdx.x >> 6;
  const int wr = wave >> 1, wc = wave & 1;
  const int row0 = blockIdx.y * 128, col0 = blockIdx.x * 128;
  const BF16* Ar = A + (size_t)row0 * K;
  const BF16* Bgr = Bg + (size_t)col0 * K;
  const BF16* Bur = Bu + (size_t)col0 * K;

  stage32(Ar, la[0], K, wave, lane);
  stage32(Bgr, lg[0], K, wave, lane);
  stage32(Bur, lu[0], K, wave, lane);
  __syncthreads();

  floatx4 accg[4][4] = {};
  floatx4 accu[4][4] = {};

  for (int kt = 0; kt < NT; ++kt) {
    const int cur = kt & 1;
    if (kt + 1 < NT) {  // prefetch next K-tile; drains at the loop barrier
      stage32(Ar + (kt + 1) * 32, la[cur ^ 1], K, wave, lane);
      stage32(Bgr + (kt + 1) * 32, lg[cur ^ 1], K, wave, lane);
      stage32(Bur + (kt + 1) * 32, lu[cur ^ 1], K, wave, lane);
    }
    short8 af[4], gf[4], uf[4];
#pragma unroll
    for (int mi = 0; mi < 4; ++mi)
      af[mi] = frag32(la[cur], wr * 64 + mi * 16 + (lane & 15), lane);
#pragma unroll
    for (int ni = 0; ni < 4; ++ni) {
      gf[ni] = frag32(lg[cur], wc * 64 + ni * 16 + (lane & 15), lane);
      uf[ni] = frag32(lu[cur], wc * 64 + ni * 16 + (lane & 15), lane);
    }
#pragma unroll
    for (int mi = 0; mi < 4; ++mi)
#pragma unroll
      for (int ni = 0; ni < 4; ++ni) {
        accg[mi][ni] = __builtin_amdgcn_mfma_f32_16x16x32_bf16(af[mi], gf[ni], accg[mi][ni], 0, 0, 0);
        accu[mi][ni] = __builtin_amdgcn_mfma_f32_16x16x32_bf16(af[mi], uf[ni], accu[mi][ni], 0, 0, 0);
      }
    __syncthreads();
  }

#pragma unroll
  for (int mi = 0; mi < 4; ++mi)
#pragma unroll
    for (int ni = 0; ni < 4; ++ni)
#pragma unroll
      for (int j = 0; j < 4; ++j) {
        int r = row0 + wr * 64 + mi * 16 + (lane >> 4) * 4 + j;
        int c = col0 + wc * 64 + ni * 16 + (lane & 15);
        float h = gelu_tanh(accg[mi][ni][j]) * accu[mi][ni][j];
        out[(size_t)r * 4096 + c] = __float2bfloat16(h);
      }
}

// ---------------------------------------------------------------------------
// Grouped dual up-GEMM (experts): 128x64 tile, BK=64, 2-phase dbuf.
// out[9216][512] = gelu(A_g@Wg_e)*(A_g@Wu_e)*row_w
// ---------------------------------------------------------------------------
__launch_bounds__(256, 2)
__global__ void gemm_up_exp(const BF16* __restrict__ A, const BF16* __restrict__ Bg,
                            const BF16* __restrict__ Bu, const int2* __restrict__ desc,
                            const float* __restrict__ row_w, BF16* __restrict__ out) {
  constexpr int K = 1024, NT = K / 64;
  __shared__ __align__(16) BF16 la[2][128 * 64];
  __shared__ __align__(16) BF16 lg[2][64 * 64];
  __shared__ __align__(16) BF16 lu[2][64 * 64];
  int2 d = desc[blockIdx.y];
  if (d.x < 0) return;
  const int e = d.x, r0 = d.y;
  const int c0 = blockIdx.x * 64;
  const int lane = threadIdx.x & 63, wave = threadIdx.x >> 6;
  const int wr = wave >> 1, wc = wave & 1;
  const BF16* Ar = A + (size_t)r0 * K;
  const BF16* Bgr = Bg + (size_t)(e * 512 + c0) * K;
  const BF16* Bur = Bu + (size_t)(e * 512 + c0) * K;

  stage64t<128>(Ar, la[0], K, wave, lane);
  stage64t<64>(Bgr, lg[0], K, wave, lane);
  stage64t<64>(Bur, lu[0], K, wave, lane);
  __syncthreads();

  floatx4 accg[4][2] = {};
  floatx4 accu[4][2] = {};

  for (int kt = 0; kt < NT; ++kt) {
    const int cur = kt & 1;
    if (kt + 1 < NT) {
      stage64t<128>(Ar + (kt + 1) * 64, la[cur ^ 1], K, wave, lane);
      stage64t<64>(Bgr + (kt + 1) * 64, lg[cur ^ 1], K, wave, lane);
      stage64t<64>(Bur + (kt + 1) * 64, lu[cur ^ 1], K, wave, lane);
    }
#pragma unroll
    for (int kh = 0; kh < 2; ++kh) {
      short8 af[4], gf[2], uf[2];
#pragma unroll
      for (int mi = 0; mi < 4; ++mi)
        af[mi] = frag64(la[cur], wr * 64 + mi * 16 + (lane & 15), kh, lane);
#pragma unroll
      for (int ni = 0; ni < 2; ++ni) {
        gf[ni] = frag64(lg[cur], wc * 32 + ni * 16 + (lane & 15), kh, lane);
        uf[ni] = frag64(lu[cur], wc * 32 + ni * 16 + (lane & 15), kh, lane);
      }
#pragma unroll
      for (int mi = 0; mi < 4; ++mi)
#pragma unroll
        for (int ni = 0; ni < 2; ++ni) {
          accg[mi][ni] = __builtin_amdgcn_mfma_f32_16x16x32_bf16(af[mi], gf[ni], accg[mi][ni], 0, 0, 0);
          accu[mi][ni] = __builtin_amdgcn_mfma_f32_16x16x32_bf16(af[mi], uf[ni], accu[mi][ni], 0, 0, 0);
        }
    }
    __syncthreads();
  }

#pragma unroll
  for (int mi = 0; mi < 4; ++mi)
#pragma unroll
    for (int ni = 0; ni < 2; ++ni)
#pragma unroll
      for (int j = 0; j < 4; ++j) {
        int r = r0 + wr * 64 + mi * 16 + (lane >> 4) * 4 + j;
        int c = c0 + wc * 32 + ni * 16 + (lane & 15);
        float h = gelu_tanh(accg[mi][ni][j]) * accu[mi][ni][j] * row_w[r];
        out[(size_t)r * 512 + c] = __float2bfloat16(h);
      }
}

// ---------------------------------------------------------------------------
// Down GEMM, 128x128, BK=64, 2-phase dbuf, bf16 store.
// GROUPED=0: A=HBUF[4096][4096], B=WddT[1024][4096], split-K=2 via z,
//            out = dp + z*4096*1024 (bf16 partials, summed in finalize)
// GROUPED=1: A=HBUF_e[9216][512], B=WdeT_e+e*1024*512, K=512, out=down_e
// ---------------------------------------------------------------------------
template <int GROUPED>
__launch_bounds__(256, 2)
__global__ void gemm_down_p(const BF16* __restrict__ A, const BF16* __restrict__ B,
                            const int2* __restrict__ desc, BF16* __restrict__ outp) {
  __shared__ __align__(16) BF16 la[2][128 * 64];
  __shared__ __align__(16) BF16 lb[2][128 * 64];
  int e = 0, r0;
  const int c0 = blockIdx.x * 128;
  if (GROUPED) {
    int2 d = desc[blockIdx.y];
    if (d.x < 0) return;
    e = d.x;
    r0 = d.y;
  } else {
    r0 = blockIdx.y * 128;
  }
  const int ldA = GROUPED ? 512 : 4096;
  const int NT = GROUPED ? 8 : 32;  // grouped K=512; dense K-half=2048
  const int lane = threadIdx.x & 63, wave = threadIdx.x >> 6;
  const int wr = wave >> 1, wc = wave & 1;
  const BF16* Ar = A + (size_t)r0 * ldA + (GROUPED ? 0 : blockIdx.z * 2048);
  const BF16* Br = GROUPED ? B + (size_t)e * 1024 * 512 + (size_t)c0 * 512
                           : B + (size_t)c0 * 4096 + blockIdx.z * 2048;
  if (!GROUPED) outp += (size_t)blockIdx.z * 4096 * 1024;

  stage64t<128>(Ar, la[0], ldA, wave, lane);
  stage64t<128>(Br, lb[0], ldA, wave, lane);
  __syncthreads();

  floatx4 acc[4][4] = {};

  for (int kt = 0; kt < NT; ++kt) {
    const int cur = kt & 1;
    if (kt + 1 < NT) {
      stage64t<128>(Ar + (kt + 1) * 64, la[cur ^ 1], ldA, wave, lane);
      stage64t<128>(Br + (kt + 1) * 64, lb[cur ^ 1], ldA, wave, lane);
    }
#pragma unroll
    for (int kh = 0; kh < 2; ++kh) {
      short8 af[4], bf[4];
#pragma unroll
      for (int mi = 0; mi < 4; ++mi)
        af[mi] = frag64(la[cur], wr * 64 + mi * 16 + (lane & 15), kh, lane);
#pragma unroll
      for (int ni = 0; ni < 4; ++ni)
        bf[ni] = frag64(lb[cur], wc * 64 + ni * 16 + (lane & 15), kh, lane);
#pragma unroll
      for (int mi = 0; mi < 4; ++mi)
#pragma unroll
        for (int ni = 0; ni < 4; ++ni)
          acc[mi][ni] = __builtin_amdgcn_mfma_f32_16x16x32_bf16(af[mi], bf[ni], acc[mi][ni], 0, 0, 0);
    }
    __syncthreads();
  }

#pragma unroll
  for (int mi = 0; mi < 4; ++mi)
#pragma unroll
    for (int ni = 0; ni < 4; ++ni)
#pragma unroll
      for (int j = 0; j < 4; ++j) {
        int r = r0 + wr * 64 + mi * 16 + (lane >> 4) * 4 + j;
        int c = c0 + wc * 64 + ni * 16 + (lane & 15);
        outp[(size_t)r * 1024 + c] = __float2bfloat16(acc[mi][ni][j]);
      }
}

// ---------------------------------------------------------------------------
// Router: rmsnorm stats, xr (w_pre2, bf16), logits, softmax, top-2.
// ---------------------------------------------------------------------------
__global__ void router_kernel(const float* __restrict__ residual,
                              const float* __restrict__ w_pre2,
                              const float* __restrict__ router_scale,
                              const float* __restrict__ per_expert_scale,
                              const float* __restrict__ Wr,  // [1024][8]
                              BF16* __restrict__ xr,         // [4096][1024]
                              int* __restrict__ top_i, float* __restrict__ top_w,
                              int* __restrict__ counts) {
  const int lane = threadIdx.x & 63, wave = threadIdx.x >> 6;
  const int n = blockIdx.x * 4 + wave;
  const float* res = residual + (size_t)n * 1024;

  float v[16];
  float ss = 0.f;
#pragma unroll
  for (int i = 0; i < 16; ++i) {
    v[i] = res[lane + i * 64];
    ss += v[i] * v[i];
  }
#pragma unroll
  for (int off = 32; off; off >>= 1) ss += __shfl_xor(ss, off);
  const float inv = rsqrtf(ss * (1.f / 1024.f) + 1e-6f);

  float logits[8] = {};
#pragma unroll
  for (int i = 0; i < 16; ++i) {
    int h = lane + i * 64;
    float nv = v[i] * inv;
    xr[(size_t)n * 1024 + h] = __float2bfloat16(nv * w_pre2[h]);
    float yv = nv * router_scale[h];
#pragma unroll
    for (int ex = 0; ex < 8; ++ex) logits[ex] += yv * Wr[h * 8 + ex];
  }
#pragma unroll
  for (int ex = 0; ex < 8; ++ex)
#pragma unroll
    for (int off = 32; off; off >>= 1) logits[ex] += __shfl_xor(logits[ex], off);

  if (lane == 0) {
    const float hscale = 0.03125f;  // 1024^-0.5
    float mx = -1e30f;
#pragma unroll
    for (int ex = 0; ex < 8; ++ex) {
      logits[ex] *= hscale;
      mx = fmaxf(mx, logits[ex]);
    }
    float p[8];
#pragma unroll
    for (int ex = 0; ex < 8; ++ex) p[ex] = __expf(logits[ex] - mx);
    int i0 = 0;
#pragma unroll
    for (int ex = 1; ex < 8; ++ex)
      if (p[ex] > p[i0]) i0 = ex;
    int i1 = -1;
#pragma unroll
    for (int ex = 0; ex < 8; ++ex)
      if (ex != i0 && (i1 < 0 || p[ex] > p[i1])) i1 = ex;
    float w0 = p[i0], w1 = p[i1];
    float swv = w0 + w1;
    w0 = w0 / swv * per_expert_scale[i0];
    w1 = w1 / swv * per_expert_scale[i1];
    top_i[n * 2] = i0;
    top_i[n * 2 + 1] = i1;
    top_w[n * 2] = w0;
    top_w[n * 2 + 1] = w1;
    atomicAdd(&counts[i0], 1);
    atomicAdd(&counts[i1], 1);
  }
}

__global__ void init_counts(int* counts) {
  if (threadIdx.x < 8) counts[threadIdx.x] = 0;
}

__global__ void moe_scan(const int* __restrict__ counts, int* __restrict__ offsets,
                         int* __restrict__ cursor, int2* __restrict__ desc,
                         int* __restrict__ row_token, float* __restrict__ row_w) {
  if (threadIdx.x == 0) {
    int acc = 0, t = 0;
    for (int e = 0; e < 8; ++e) {
      offsets[e] = acc;
      cursor[e] = 0;
      int cnt = counts[e];
      int ntile = (cnt + 127) >> 7;
      for (int k = 0; k < ntile; ++k) desc[t++] = make_int2(e, acc + k * 128);
      acc += ntile * 128;
    }
    for (; t < 72; ++t) desc[t] = make_int2(-1, 0);
  }
  for (int i = threadIdx.x; i < 9216; i += blockDim.x) {
    row_token[i] = -1;
    row_w[i] = 0.f;
  }
}

__global__ void moe_assign(const int* __restrict__ top_i, const float* __restrict__ top_w,
                           const int* __restrict__ offsets, int* __restrict__ cursor,
                           int* __restrict__ row_token, float* __restrict__ row_w,
                           int* __restrict__ pair_pos) {
  const int p = blockIdx.x * blockDim.x + threadIdx.x;  // 0..8191
  const int e = top_i[p];
  const int pos = offsets[e] + atomicAdd(&cursor[e], 1);
  row_token[pos] = p >> 1;
  row_w[pos] = top_w[p];
  pair_pos[p] = pos;
}

__global__ void moe_gather(const BF16* __restrict__ xr, const int* __restrict__ row_token,
                           BF16* __restrict__ A_g) {
  const int r = blockIdx.x;
  const int t = row_token[r];
  uint2* dst = (uint2*)(A_g + (size_t)r * 1024) + threadIdx.x;
  if (t < 0) {
    uint2 z;
    z.x = 0u;
    z.y = 0u;
    *dst = z;
  } else {
    *dst = *((const uint2*)(xr + (size_t)t * 1024) + threadIdx.x);
  }
}

// ---------------------------------------------------------------------------
// Finalize: dense = dp0+dp1 (bf16 split-K partials); routed = down_e[p0]+[p1];
// out = rmsnorm(dense)*w_post1 + rmsnorm(routed)*w_post2
// ---------------------------------------------------------------------------
__global__ void finalize_kernel(const BF16* __restrict__ dp0, const BF16* __restrict__ dp1,
                                const BF16* __restrict__ de,
                                const int* __restrict__ pair_pos,
                                const float* __restrict__ w1, const float* __restrict__ w2,
                                float* __restrict__ out) {
  const int n = blockIdx.x, t = threadIdx.x;
  const int p0 = pair_pos[n * 2], p1 = pair_pos[n * 2 + 1];
  float d[4], r[4];
  float ssd = 0.f, ssr = 0.f;
#pragma unroll
  for (int i = 0; i < 4; ++i) {
    int h = t + i * 256;
    d[i] = __bfloat162float(dp0[(size_t)n * 1024 + h]) +
           __bfloat162float(dp1[(size_t)n * 1024 + h]);
    r[i] = __bfloat162float(de[(size_t)p0 * 1024 + h]) +
           __bfloat162float(de[(size_t)p1 * 1024 + h]);
    ssd += d[i] * d[i];
    ssr += r[i] * r[i];
  }
#pragma unroll
  for (int off = 32; off; off >>= 1) {
    ssd += __shfl_xor(ssd, off);
    ssr += __shfl_xor(ssr, off);
  }
  __shared__ float sd[4], sr[4];
  int wave = t >> 6, lane = t & 63;
  if (lane == 0) {
    sd[wave] = ssd;
    sr[wave] = ssr;
  }
  __syncthreads();
  ssd = sd[0] + sd[1] + sd[2] + sd[3];
  ssr = sr[0] + sr[1] + sr[2] + sr[3];
  const float invd = rsqrtf(ssd * (1.f / 1024.f) + 1e-6f);
  const float invr = rsqrtf(ssr * (1.f / 1024.f) + 1e-6f);
#pragma unroll
  for (int i = 0; i < 4; ++i) {
    int h = t + i * 256;
    out[(size_t)n * 1024 + h] = d[i] * invd * w1[h] + r[i] * invr * w2[h];
  }
}

// ---------------------------------------------------------------------------
__global__ void transpose_cvt(const float* __restrict__ in, BF16* __restrict__ out,
                              int rows, int cols) {
  __shared__ float tile[32][33];
  const size_t boff = (size_t)blockIdx.z * rows * cols;
  in += boff;
  out += boff;
  const int c0 = blockIdx.x * 32, r0 = blockIdx.y * 32;
#pragma unroll
  for (int i = 0; i < 4; ++i)
    tile[threadIdx.y + i * 8][threadIdx.x] =
        in[(size_t)(r0 + threadIdx.y + i * 8) * cols + c0 + threadIdx.x];
  __syncthreads();
#pragma unroll
  for (int i = 0; i < 4; ++i)
    out[(size_t)(c0 + threadIdx.y + i * 8) * rows + r0 + threadIdx.x] =
        __float2bfloat16(tile[threadIdx.x][threadIdx.y + i * 8]);
}

__global__ void cvt_bf16_kernel(const float* __restrict__ in, BF16* __restrict__ out) {
  const size_t i = ((size_t)blockIdx.x * blockDim.x + threadIdx.x) * 4;
  float4 v = *(const float4*)(in + i);
  BF16 o[4] = {__float2bfloat16(v.x), __float2bfloat16(v.y),
               __float2bfloat16(v.z), __float2bfloat16(v.w)};
  *(uint2*)(out + i) = *(const uint2*)o;
}

// ---------------------------------------------------------------------------
extern "C" void kernel_launch(void* const* d_in, const int* in_sizes, int n_in,
                              void* d_out, int out_size, void* d_ws, size_t ws_size,
                              hipStream_t stream) {
  const float* x = (const float*)d_in[0];
  const float* res = (const float*)d_in[1];
  const float* Wg_d = (const float*)d_in[2];
  const float* Wu_d = (const float*)d_in[3];
  const float* Wd_d = (const float*)d_in[4];
  const float* w_post1 = (const float*)d_in[5];
  const float* w_pre2 = (const float*)d_in[6];
  const float* w_post2 = (const float*)d_in[7];
  const float* router_scale = (const float*)d_in[8];
  const float* per_expert_scale = (const float*)d_in[9];
  const float* Wr = (const float*)d_in[10];
  const float* Wg_e = (const float*)d_in[11];
  const float* Wu_e = (const float*)d_in[12];
  const float* Wd_e = (const float*)d_in[13];
  float* out = (float*)d_out;

  char* ws = (char*)d_ws;
  const size_t MB = 1ull << 20;
  BF16* x_b = (BF16*)(ws + 0 * MB);      // [4096][1024]
  BF16* xr_b = (BF16*)(ws + 8 * MB);     // [4096][1024] (dead after gather)
  BF16* dp01 = (BF16*)(ws + 8 * MB);     // [2][4096][1024] split-K partials
                                         //   (aliases xr_b + WgdT, both dead)
  BF16* WgdT = (BF16*)(ws + 16 * MB);    // [4096][1024] (dead after dense up)
  BF16* WudT = (BF16*)(ws + 24 * MB);    // [4096][1024]
  BF16* WddT = (BF16*)(ws + 32 * MB);    // [1024][4096]
  BF16* WgeT = (BF16*)(ws + 40 * MB);    // [8][512][1024]
  BF16* WueT = (BF16*)(ws + 48 * MB);    // [8][512][1024]
  BF16* WdeT_e = (BF16*)(ws + 56 * MB);  // [8][1024][512]
  BF16* HBUF = (BF16*)(ws + 64 * MB);    // [4096][4096] (dead after dense down)
  BF16* down_e = (BF16*)(ws + 64 * MB);  // [9216][1024] (reuses HBUF)
  BF16* A_g = (BF16*)(ws + 96 * MB);     // [9216][1024]
  BF16* HBUF_e = (BF16*)(ws + 114 * MB); // [9216][512]
  char* S = ws + 123 * MB;
  int* top_i = (int*)(S);                  // [8192]
  float* top_w = (float*)(S + 32 * 1024);  // [8192]
  int* pair_pos = (int*)(S + 64 * 1024);   // [8192]
  int* row_token = (int*)(S + 96 * 1024);  // [9216]
  float* row_w = (float*)(S + 136 * 1024); // [9216]
  int* counts = (int*)(S + 176 * 1024);    // [8]
  int* offsets = counts + 8;
  int* cursor = counts + 16;
  int2* desc = (int2*)(counts + 24);       // [72]

  dim3 tb(32, 8);
  // pre-pass: conversions + weight transposes (B^T layout, bf16)
  cvt_bf16_kernel<<<4096, 256, 0, stream>>>(x, x_b);
  transpose_cvt<<<dim3(128, 32, 1), tb, 0, stream>>>(Wg_d, WgdT, 1024, 4096);
  transpose_cvt<<<dim3(128, 32, 1), tb, 0, stream>>>(Wu_d, WudT, 1024, 4096);
  transpose_cvt<<<dim3(32, 128, 1), tb, 0, stream>>>(Wd_d, WddT, 4096, 1024);
  transpose_cvt<<<dim3(16, 32, 8), tb, 0, stream>>>(Wg_e, WgeT, 1024, 512);
  transpose_cvt<<<dim3(16, 32, 8), tb, 0, stream>>>(Wu_e, WueT, 1024, 512);
  transpose_cvt<<<dim3(32, 16, 8), tb, 0, stream>>>(Wd_e, WdeT_e, 512, 1024);

  // router + MoE bookkeeping
  init_counts<<<1, 64, 0, stream>>>(counts);
  router_kernel<<<1024, 256, 0, stream>>>(res, w_pre2, router_scale, per_expert_scale,
                                          Wr, xr_b, top_i, top_w, counts);
  moe_scan<<<1, 256, 0, stream>>>(counts, offsets, cursor, desc, row_token, row_w);
  moe_assign<<<32, 256, 0, stream>>>(top_i, top_w, offsets, cursor, row_token, row_w,
                                     pair_pos);
  moe_gather<<<9216, 256, 0, stream>>>(xr_b, row_token, A_g);

  // dense path (dp01 overwrites xr_b/WgdT which are dead by now)
  gemm_up_dense<<<dim3(32, 32), 256, 0, stream>>>(x_b, WgdT, WudT, HBUF);
  gemm_down_p<0><<<dim3(8, 32, 2), 256, 0, stream>>>(HBUF, WddT, nullptr, dp01);

  // expert path (grouped; combine weight folded into hidden)
  gemm_up_exp<<<dim3(8, 72), 256, 0, stream>>>(A_g, WgeT, WueT, desc, row_w, HBUF_e);
  gemm_down_p<1><<<dim3(8, 72), 256, 0, stream>>>(HBUF_e, WdeT_e, desc, down_e);

  // out = rmsnorm(dense)*w_post1 + rmsnorm(routed)*w_post2
  finalize_kernel<<<4096, 256, 0, stream>>>(dp01, dp01 + 4096 * 1024, down_e, pair_pos,
                                            w_post1, w_post2, out);
}

// Round 6
// 569.098 us; speedup vs baseline: 1.0194x; 1.0194x over previous
//
#include <hip/hip_runtime.h>
#include <hip/hip_bf16.h>
#include <cstdint>

// ---------------------------------------------------------------------------
// Gemma4 MoE FFN. N=4096 tokens, H=1024, ID=4096, IM=512, E=8, top-2.
// Round 6: all GEMMs as PLAIN 128x128 m97-structure kernels (single-buffer,
// BK=64, granule-XOR swizzle, 3 blocks/CU via __launch_bounds__(256,3)).
// gelu-mul fused into the U-GEMM epilogue (reads G). Expert GEMMs read token
// rows via row_token indirection (no gather). Dense down = split-K2 partials.
// ---------------------------------------------------------------------------

typedef __attribute__((ext_vector_type(8))) short short8;
typedef __attribute__((ext_vector_type(4))) float floatx4;
typedef const void __attribute__((address_space(1)))* gptr_t;
typedef void __attribute__((address_space(3)))* sptr_t;

#define BF16 __hip_bfloat16

__device__ __forceinline__ float gelu_tanh(float x) {
  float x3 = x * x * x;
  float t = tanhf(0.7978845608028654f * (x + 0.044715f * x3));
  return 0.5f * x * (1.f + t);
}

// ---------------------------------------------------------------------------
// [128][64] bf16 tile staging, granule-XOR swizzle (round-4 measured:
// SQ_LDS_BANK_CONFLICT -> 0). LDS slot g holds source granule g ^ (row&7).
// 256-thread block: wave w stages rows w*32..w*32+31, 4 loads/thread.
// ---------------------------------------------------------------------------
__device__ __forceinline__ void stage128x64(const BF16* __restrict__ g, BF16* lds,
                                            int ldg, int wave, int lane) {
  const int rsub = lane >> 3;  // 0..7
  const int gcol = lane & 7;   // 0..7
#pragma unroll
  for (int j = 0; j < 4; ++j) {
    int row = wave * 32 + j * 8 + rsub;
    const BF16* src = g + (size_t)row * ldg + ((gcol ^ rsub) * 8);
    BF16* dst = lds + (wave * 32 + j * 8) * 64;  // wave-uniform base; HW adds lane*16B
    __builtin_amdgcn_global_load_lds((gptr_t)src, (sptr_t)dst, 16, 0, 0);
  }
}

// Indirect variant: row r0+row is token row_token[r0+row] of xr (tok pre-hoisted).
__device__ __forceinline__ void stage128x64_indir(const BF16* __restrict__ xr,
                                                  const int* __restrict__ tok,
                                                  int kofs, BF16* lds, int wave, int lane) {
  const int rsub = lane >> 3;
  const int gcol = lane & 7;
#pragma unroll
  for (int j = 0; j < 4; ++j) {
    const BF16* src = xr + (size_t)tok[j] * 1024 + kofs + ((gcol ^ rsub) * 8);
    BF16* dst = lds + (wave * 32 + j * 8) * 64;
    __builtin_amdgcn_global_load_lds((gptr_t)src, (sptr_t)dst, 16, 0, 0);
  }
}

__device__ __forceinline__ short8 frag64(const BF16* lds, int fr, int kh, int lane) {
  int gk = kh * 4 + (lane >> 4);
  return *(const short8*)&lds[fr * 64 + ((gk ^ (fr & 7)) * 8)];
}

// ---------------------------------------------------------------------------
// Unified plain GEMM: C[128x128] tile, A [M][lda] bf16 (row-major),
// B = B^T [N][ldb] bf16 (row r = output col), K = nkt*64 (+ z split offset).
// EPI: 0 = plain bf16 store; 1 = gelu(G)*acc; 2 = gelu(G)*acc*row_w[r]
// INDIR: A rows via row_token (experts, padded rows -> token 0, row_w=0)
// GROUPED: {expert,row0} from desc[blockIdx.y]; B rows offset by e*eB
// ---------------------------------------------------------------------------
template <int EPI, int INDIR, int GROUPED>
__launch_bounds__(256, 3)
__global__ void gemm_bt(const BF16* __restrict__ A, int lda,
                        const BF16* __restrict__ B, int ldb, int eB,
                        const int2* __restrict__ desc,
                        const int* __restrict__ row_token,
                        const BF16* __restrict__ G, const float* __restrict__ row_w,
                        BF16* __restrict__ out, int ldo, size_t zstride, int nkt) {
  __shared__ __align__(16) BF16 la[128 * 64];
  __shared__ __align__(16) BF16 lb[128 * 64];
  int e = 0, r0;
  const int c0 = blockIdx.x * 128;
  if (GROUPED) {
    int2 d = desc[blockIdx.y];
    if (d.x < 0) return;
    e = d.x;
    r0 = d.y;
  } else {
    r0 = blockIdx.y * 128;
  }
  const int lane = threadIdx.x & 63, wave = threadIdx.x >> 6;
  const int wr = wave >> 1, wc = wave & 1;
  const int k0 = blockIdx.z * nkt * 64;
  const BF16* Ar = A + (size_t)r0 * lda + k0;
  const BF16* Br = B + (size_t)(GROUPED ? e * eB + c0 : c0) * ldb + k0;
  out += (size_t)blockIdx.z * zstride;

  int tok[4];
  if (INDIR) {
#pragma unroll
    for (int j = 0; j < 4; ++j) {
      int t = row_token[r0 + wave * 32 + j * 8 + (lane >> 3)];
      tok[j] = t < 0 ? 0 : t;
    }
  }

  floatx4 acc[4][4] = {};

  for (int kt = 0; kt < nkt; ++kt) {
    if (INDIR)
      stage128x64_indir(A + k0, tok, kt * 64, la, wave, lane);
    else
      stage128x64(Ar + kt * 64, la, lda, wave, lane);
    stage128x64(Br + kt * 64, lb, ldb, wave, lane);
    __syncthreads();
#pragma unroll
    for (int kh = 0; kh < 2; ++kh) {
      short8 af[4], bf[4];
#pragma unroll
      for (int mi = 0; mi < 4; ++mi)
        af[mi] = frag64(la, wr * 64 + mi * 16 + (lane & 15), kh, lane);
#pragma unroll
      for (int ni = 0; ni < 4; ++ni)
        bf[ni] = frag64(lb, wc * 64 + ni * 16 + (lane & 15), kh, lane);
#pragma unroll
      for (int mi = 0; mi < 4; ++mi)
#pragma unroll
        for (int ni = 0; ni < 4; ++ni)
          acc[mi][ni] = __builtin_amdgcn_mfma_f32_16x16x32_bf16(af[mi], bf[ni], acc[mi][ni], 0, 0, 0);
    }
    __syncthreads();
  }

  // Epilogue. C/D layout: col=lane&15, row=(lane>>4)*4+j [m89-verified]
  float rw[4][4];
  if (EPI == 2) {
#pragma unroll
    for (int mi = 0; mi < 4; ++mi)
#pragma unroll
      for (int j = 0; j < 4; ++j)
        rw[mi][j] = row_w[r0 + wr * 64 + mi * 16 + (lane >> 4) * 4 + j];
  }
#pragma unroll
  for (int mi = 0; mi < 4; ++mi)
#pragma unroll
    for (int ni = 0; ni < 4; ++ni)
#pragma unroll
      for (int j = 0; j < 4; ++j) {
        int r = r0 + wr * 64 + mi * 16 + (lane >> 4) * 4 + j;
        int c = c0 + wc * 64 + ni * 16 + (lane & 15);
        float v = acc[mi][ni][j];
        if (EPI >= 1) {
          float g = __bfloat162float(G[(size_t)r * ldo + c]);
          v = gelu_tanh(g) * v;
        }
        if (EPI == 2) v *= rw[mi][j];
        out[(size_t)r * ldo + c] = __float2bfloat16(v);
      }
}

// ---------------------------------------------------------------------------
// Router: rmsnorm stats, xr (w_pre2, bf16), logits, softmax, top-2.
// ---------------------------------------------------------------------------
__global__ void router_kernel(const float* __restrict__ residual,
                              const float* __restrict__ w_pre2,
                              const float* __restrict__ router_scale,
                              const float* __restrict__ per_expert_scale,
                              const float* __restrict__ Wr,  // [1024][8]
                              BF16* __restrict__ xr,         // [4096][1024]
                              int* __restrict__ top_i, float* __restrict__ top_w,
                              int* __restrict__ counts) {
  const int lane = threadIdx.x & 63, wave = threadIdx.x >> 6;
  const int n = blockIdx.x * 4 + wave;
  const float* res = residual + (size_t)n * 1024;

  float v[16];
  float ss = 0.f;
#pragma unroll
  for (int i = 0; i < 16; ++i) {
    v[i] = res[lane + i * 64];
    ss += v[i] * v[i];
  }
#pragma unroll
  for (int off = 32; off; off >>= 1) ss += __shfl_xor(ss, off);
  const float inv = rsqrtf(ss * (1.f / 1024.f) + 1e-6f);

  float logits[8] = {};
#pragma unroll
  for (int i = 0; i < 16; ++i) {
    int h = lane + i * 64;
    float nv = v[i] * inv;
    xr[(size_t)n * 1024 + h] = __float2bfloat16(nv * w_pre2[h]);
    float yv = nv * router_scale[h];
#pragma unroll
    for (int ex = 0; ex < 8; ++ex) logits[ex] += yv * Wr[h * 8 + ex];
  }
#pragma unroll
  for (int ex = 0; ex < 8; ++ex)
#pragma unroll
    for (int off = 32; off; off >>= 1) logits[ex] += __shfl_xor(logits[ex], off);

  if (lane == 0) {
    const float hscale = 0.03125f;  // 1024^-0.5
    float mx = -1e30f;
#pragma unroll
    for (int ex = 0; ex < 8; ++ex) {
      logits[ex] *= hscale;
      mx = fmaxf(mx, logits[ex]);
    }
    float p[8];
#pragma unroll
    for (int ex = 0; ex < 8; ++ex) p[ex] = __expf(logits[ex] - mx);
    int i0 = 0;
#pragma unroll
    for (int ex = 1; ex < 8; ++ex)
      if (p[ex] > p[i0]) i0 = ex;
    int i1 = -1;
#pragma unroll
    for (int ex = 0; ex < 8; ++ex)
      if (ex != i0 && (i1 < 0 || p[ex] > p[i1])) i1 = ex;
    float w0 = p[i0], w1 = p[i1];
    float swv = w0 + w1;
    w0 = w0 / swv * per_expert_scale[i0];
    w1 = w1 / swv * per_expert_scale[i1];
    top_i[n * 2] = i0;
    top_i[n * 2 + 1] = i1;
    top_w[n * 2] = w0;
    top_w[n * 2 + 1] = w1;
    atomicAdd(&counts[i0], 1);
    atomicAdd(&counts[i1], 1);
  }
}

__global__ void init_counts(int* counts) {
  if (threadIdx.x < 8) counts[threadIdx.x] = 0;
}

__global__ void moe_scan(const int* __restrict__ counts, int* __restrict__ offsets,
                         int* __restrict__ cursor, int2* __restrict__ desc,
                         int* __restrict__ row_token, float* __restrict__ row_w) {
  if (threadIdx.x == 0) {
    int acc = 0, t = 0;
    for (int e = 0; e < 8; ++e) {
      offsets[e] = acc;
      cursor[e] = 0;
      int cnt = counts[e];
      int ntile = (cnt + 127) >> 7;
      for (int k = 0; k < ntile; ++k) desc[t++] = make_int2(e, acc + k * 128);
      acc += ntile * 128;
    }
    for (; t < 72; ++t) desc[t] = make_int2(-1, 0);
  }
  for (int i = threadIdx.x; i < 9216; i += blockDim.x) {
    row_token[i] = -1;
    row_w[i] = 0.f;
  }
}

__global__ void moe_assign(const int* __restrict__ top_i, const float* __restrict__ top_w,
                           const int* __restrict__ offsets, int* __restrict__ cursor,
                           int* __restrict__ row_token, float* __restrict__ row_w,
                           int* __restrict__ pair_pos) {
  const int p = blockIdx.x * blockDim.x + threadIdx.x;  // 0..8191
  const int e = top_i[p];
  const int pos = offsets[e] + atomicAdd(&cursor[e], 1);
  row_token[pos] = p >> 1;
  row_w[pos] = top_w[p];
  pair_pos[p] = pos;
}

// ---------------------------------------------------------------------------
// Finalize: dense = dp0+dp1 (split-K partials); routed = down_e[p0]+down_e[p1]
// out = rmsnorm(dense)*w_post1 + rmsnorm(routed)*w_post2
// ---------------------------------------------------------------------------
__global__ void finalize_kernel(const BF16* __restrict__ dp0, const BF16* __restrict__ dp1,
                                const BF16* __restrict__ de,
                                const int* __restrict__ pair_pos,
                                const float* __restrict__ w1, const float* __restrict__ w2,
                                float* __restrict__ out) {
  const int n = blockIdx.x, t = threadIdx.x;
  const int p0 = pair_pos[n * 2], p1 = pair_pos[n * 2 + 1];
  float d[4], r[4];
  float ssd = 0.f, ssr = 0.f;
#pragma unroll
  for (int i = 0; i < 4; ++i) {
    int h = t + i * 256;
    d[i] = __bfloat162float(dp0[(size_t)n * 1024 + h]) +
           __bfloat162float(dp1[(size_t)n * 1024 + h]);
    r[i] = __bfloat162float(de[(size_t)p0 * 1024 + h]) +
           __bfloat162float(de[(size_t)p1 * 1024 + h]);
    ssd += d[i] * d[i];
    ssr += r[i] * r[i];
  }
#pragma unroll
  for (int off = 32; off; off >>= 1) {
    ssd += __shfl_xor(ssd, off);
    ssr += __shfl_xor(ssr, off);
  }
  __shared__ float sd[4], sr[4];
  int wave = t >> 6, lane = t & 63;
  if (lane == 0) {
    sd[wave] = ssd;
    sr[wave] = ssr;
  }
  __syncthreads();
  ssd = sd[0] + sd[1] + sd[2] + sd[3];
  ssr = sr[0] + sr[1] + sr[2] + sr[3];
  const float invd = rsqrtf(ssd * (1.f / 1024.f) + 1e-6f);
  const float invr = rsqrtf(ssr * (1.f / 1024.f) + 1e-6f);
#pragma unroll
  for (int i = 0; i < 4; ++i) {
    int h = t + i * 256;
    out[(size_t)n * 1024 + h] = d[i] * invd * w1[h] + r[i] * invr * w2[h];
  }
}

// ---------------------------------------------------------------------------
__global__ void transpose_cvt(const float* __restrict__ in, BF16* __restrict__ out,
                              int rows, int cols) {
  __shared__ float tile[32][33];
  const size_t boff = (size_t)blockIdx.z * rows * cols;
  in += boff;
  out += boff;
  const int c0 = blockIdx.x * 32, r0 = blockIdx.y * 32;
#pragma unroll
  for (int i = 0; i < 4; ++i)
    tile[threadIdx.y + i * 8][threadIdx.x] =
        in[(size_t)(r0 + threadIdx.y + i * 8) * cols + c0 + threadIdx.x];
  __syncthreads();
#pragma unroll
  for (int i = 0; i < 4; ++i)
    out[(size_t)(c0 + threadIdx.y + i * 8) * rows + r0 + threadIdx.x] =
        __float2bfloat16(tile[threadIdx.x][threadIdx.y + i * 8]);
}

__global__ void cvt_bf16_kernel(const float* __restrict__ in, BF16* __restrict__ out) {
  const size_t i = ((size_t)blockIdx.x * blockDim.x + threadIdx.x) * 4;
  float4 v = *(const float4*)(in + i);
  BF16 o[4] = {__float2bfloat16(v.x), __float2bfloat16(v.y),
               __float2bfloat16(v.z), __float2bfloat16(v.w)};
  *(uint2*)(out + i) = *(const uint2*)o;
}

// ---------------------------------------------------------------------------
// Workspace layout (MiB offsets; lifetime-checked aliasing):
//   0.. 8  x_b        [prepass -> dense-U]
//   0..18  down_e     [expert-down -> finalize]   (x_b/xr_b/WgdT dead by then)
//   8..16  xr_b       [router -> expert-U]
//  16..24  WgdT       [prepass -> dense-G]
//  24..32  WudT       [prepass -> dense-U]
//  32..40  WddT       [prepass -> dense-down]
//  40..48  WgeT       [prepass -> expert-G]; then dp0 [dense-down -> finalize]
//  48..56  WueT       [prepass -> expert-U]; then dp1
//  56..64  WdeT_e     [prepass -> expert-down]
//  64..96  HBUF       [dense-U -> dense-down]
//  96..128 Gbuf       [dense-G -> dense-U]
//  96..96.3 bookkeeping [router -> finalize]  (router runs AFTER dense-U)
//  97..106 G_e        [expert-G -> expert-U]
// 106..115 HBUF_e     [expert-U -> expert-down]
// Order: prepass, dense-G, dense-U, router, scan, assign, expert-G, expert-U,
//        expert-down, dense-down(split2), finalize.
// ---------------------------------------------------------------------------
extern "C" void kernel_launch(void* const* d_in, const int* in_sizes, int n_in,
                              void* d_out, int out_size, void* d_ws, size_t ws_size,
                              hipStream_t stream) {
  const float* x = (const float*)d_in[0];
  const float* res = (const float*)d_in[1];
  const float* Wg_d = (const float*)d_in[2];
  const float* Wu_d = (const float*)d_in[3];
  const float* Wd_d = (const float*)d_in[4];
  const float* w_post1 = (const float*)d_in[5];
  const float* w_pre2 = (const float*)d_in[6];
  const float* w_post2 = (const float*)d_in[7];
  const float* router_scale = (const float*)d_in[8];
  const float* per_expert_scale = (const float*)d_in[9];
  const float* Wr = (const float*)d_in[10];
  const float* Wg_e = (const float*)d_in[11];
  const float* Wu_e = (const float*)d_in[12];
  const float* Wd_e = (const float*)d_in[13];
  float* out = (float*)d_out;

  char* ws = (char*)d_ws;
  const size_t MB = 1ull << 20;
  BF16* x_b = (BF16*)(ws + 0 * MB);
  BF16* down_e = (BF16*)(ws + 0 * MB);  // [9216][1024], after x_b/xr_b/WgdT dead
  BF16* xr_b = (BF16*)(ws + 8 * MB);
  BF16* WgdT = (BF16*)(ws + 16 * MB);
  BF16* WudT = (BF16*)(ws + 24 * MB);
  BF16* WddT = (BF16*)(ws + 32 * MB);
  BF16* WgeT = (BF16*)(ws + 40 * MB);
  BF16* dp01 = (BF16*)(ws + 40 * MB);  // [2][4096][1024], after WgeT/WueT dead
  BF16* WueT = (BF16*)(ws + 48 * MB);
  BF16* WdeT_e = (BF16*)(ws + 56 * MB);
  BF16* HBUF = (BF16*)(ws + 64 * MB);   // [4096][4096]
  BF16* Gbuf = (BF16*)(ws + 96 * MB);   // [4096][4096]
  BF16* G_e = (BF16*)(ws + 97 * MB);    // [9216][512]
  BF16* HBUF_e = (BF16*)(ws + 106 * MB);// [9216][512]
  char* S = ws + 96 * MB;               // bookkeeping (post-Gbuf lifetime)
  int* top_i = (int*)(S);                  // [8192]
  float* top_w = (float*)(S + 32 * 1024);  // [8192]
  int* pair_pos = (int*)(S + 64 * 1024);   // [8192]
  int* row_token = (int*)(S + 96 * 1024);  // [9216]
  float* row_w = (float*)(S + 136 * 1024); // [9216]
  int* counts = (int*)(S + 176 * 1024);    // [8]
  int* offsets = counts + 8;
  int* cursor = counts + 16;
  int2* desc = (int2*)(counts + 24);       // [72]

  dim3 tb(32, 8);
  // pre-pass: conversions + weight transposes (B^T layout, bf16)
  cvt_bf16_kernel<<<4096, 256, 0, stream>>>(x, x_b);
  transpose_cvt<<<dim3(128, 32, 1), tb, 0, stream>>>(Wg_d, WgdT, 1024, 4096);
  transpose_cvt<<<dim3(128, 32, 1), tb, 0, stream>>>(Wu_d, WudT, 1024, 4096);
  transpose_cvt<<<dim3(32, 128, 1), tb, 0, stream>>>(Wd_d, WddT, 4096, 1024);
  transpose_cvt<<<dim3(16, 32, 8), tb, 0, stream>>>(Wg_e, WgeT, 1024, 512);
  transpose_cvt<<<dim3(16, 32, 8), tb, 0, stream>>>(Wu_e, WueT, 1024, 512);
  transpose_cvt<<<dim3(32, 16, 8), tb, 0, stream>>>(Wd_e, WdeT_e, 512, 1024);

  // dense path part 1: G = x@Wg ; HBUF = gelu(G) * (x@Wu)
  gemm_bt<0, 0, 0><<<dim3(32, 32, 1), 256, 0, stream>>>(
      x_b, 1024, WgdT, 1024, 0, nullptr, nullptr, nullptr, nullptr, Gbuf, 4096, 0, 16);
  gemm_bt<1, 0, 0><<<dim3(32, 32, 1), 256, 0, stream>>>(
      x_b, 1024, WudT, 1024, 0, nullptr, nullptr, Gbuf, nullptr, HBUF, 4096, 0, 16);

  // router + MoE bookkeeping (after dense-U so bookkeeping can live in Gbuf space)
  init_counts<<<1, 64, 0, stream>>>(counts);
  router_kernel<<<1024, 256, 0, stream>>>(res, w_pre2, router_scale, per_expert_scale,
                                          Wr, xr_b, top_i, top_w, counts);
  moe_scan<<<1, 256, 0, stream>>>(counts, offsets, cursor, desc, row_token, row_w);
  moe_assign<<<32, 256, 0, stream>>>(top_i, top_w, offsets, cursor, row_token, row_w,
                                     pair_pos);

  // expert path: G_e = xr@Wg_e ; HBUF_e = gelu(G_e)*(xr@Wu_e)*row_w ; down
  gemm_bt<0, 1, 1><<<dim3(4, 72, 1), 256, 0, stream>>>(
      xr_b, 1024, WgeT, 1024, 512, desc, row_token, nullptr, nullptr, G_e, 512, 0, 16);
  gemm_bt<2, 1, 1><<<dim3(4, 72, 1), 256, 0, stream>>>(
      xr_b, 1024, WueT, 1024, 512, desc, row_token, G_e, row_w, HBUF_e, 512, 0, 16);
  gemm_bt<0, 0, 1><<<dim3(8, 72, 1), 256, 0, stream>>>(
      HBUF_e, 512, WdeT_e, 512, 1024, desc, nullptr, nullptr, nullptr, down_e, 1024, 0, 8);

  // dense down: split-K=2, bf16 partials over dead WgeT/WueT space
  gemm_bt<0, 0, 0><<<dim3(8, 32, 2), 256, 0, stream>>>(
      HBUF, 4096, WddT, 4096, 0, nullptr, nullptr, nullptr, nullptr, dp01, 1024,
      (size_t)4096 * 1024, 32);

  // out = rmsnorm(dense)*w_post1 + rmsnorm(routed)*w_post2
  finalize_kernel<<<4096, 256, 0, stream>>>(dp01, dp01 + (size_t)4096 * 1024, down_e,
                                            pair_pos, w_post1, w_post2, out);
}

// Round 7
// 430.879 us; speedup vs baseline: 1.3464x; 1.3208x over previous
//
#include <hip/hip_runtime.h>
#include <hip/hip_bf16.h>
#include <cstdint>

// ---------------------------------------------------------------------------
// Gemma4 MoE FFN. N=4096 tokens, H=1024, ID=4096, IM=512, E=8, top-2.
// Round 7: remove global-atomic storms (router counts / assign cursor were
// ~200us of cross-XCD same-line atomic serialization). Histogram/scan/assign
// now use per-block LDS reductions, zero global atomics. GEMMs unchanged
// (plain 128x128 m97-structure, granule-XOR swizzle, 3 blocks/CU).
// ---------------------------------------------------------------------------

typedef __attribute__((ext_vector_type(8))) short short8;
typedef __attribute__((ext_vector_type(4))) float floatx4;
typedef const void __attribute__((address_space(1)))* gptr_t;
typedef void __attribute__((address_space(3)))* sptr_t;

#define BF16 __hip_bfloat16

__device__ __forceinline__ float gelu_tanh(float x) {
  float x3 = x * x * x;
  float t = tanhf(0.7978845608028654f * (x + 0.044715f * x3));
  return 0.5f * x * (1.f + t);
}

// ---------------------------------------------------------------------------
// [128][64] bf16 tile staging, granule-XOR swizzle (round-4 measured:
// SQ_LDS_BANK_CONFLICT -> 0). LDS slot g holds source granule g ^ (row&7).
// ---------------------------------------------------------------------------
__device__ __forceinline__ void stage128x64(const BF16* __restrict__ g, BF16* lds,
                                            int ldg, int wave, int lane) {
  const int rsub = lane >> 3;  // 0..7
  const int gcol = lane & 7;   // 0..7
#pragma unroll
  for (int j = 0; j < 4; ++j) {
    int row = wave * 32 + j * 8 + rsub;
    const BF16* src = g + (size_t)row * ldg + ((gcol ^ rsub) * 8);
    BF16* dst = lds + (wave * 32 + j * 8) * 64;  // wave-uniform base; HW adds lane*16B
    __builtin_amdgcn_global_load_lds((gptr_t)src, (sptr_t)dst, 16, 0, 0);
  }
}

// Indirect variant: A rows via row_token (tok pre-hoisted per thread).
__device__ __forceinline__ void stage128x64_indir(const BF16* __restrict__ xr,
                                                  const int* __restrict__ tok,
                                                  int kofs, BF16* lds, int wave, int lane) {
  const int rsub = lane >> 3;
  const int gcol = lane & 7;
#pragma unroll
  for (int j = 0; j < 4; ++j) {
    const BF16* src = xr + (size_t)tok[j] * 1024 + kofs + ((gcol ^ rsub) * 8);
    BF16* dst = lds + (wave * 32 + j * 8) * 64;
    __builtin_amdgcn_global_load_lds((gptr_t)src, (sptr_t)dst, 16, 0, 0);
  }
}

__device__ __forceinline__ short8 frag64(const BF16* lds, int fr, int kh, int lane) {
  int gk = kh * 4 + (lane >> 4);
  return *(const short8*)&lds[fr * 64 + ((gk ^ (fr & 7)) * 8)];
}

// ---------------------------------------------------------------------------
// Unified plain GEMM: C[128x128] tile, A [M][lda] bf16, B = B^T [N][ldb] bf16.
// EPI: 0 = plain store; 1 = gelu(G)*acc; 2 = gelu(G)*acc*row_w[r]
// INDIR: A rows via row_token.  GROUPED: {expert,row0} from desc[blockIdx.y].
// ---------------------------------------------------------------------------
template <int EPI, int INDIR, int GROUPED>
__launch_bounds__(256, 3)
__global__ void gemm_bt(const BF16* __restrict__ A, int lda,
                        const BF16* __restrict__ B, int ldb, int eB,
                        const int2* __restrict__ desc,
                        const int* __restrict__ row_token,
                        const BF16* __restrict__ G, const float* __restrict__ row_w,
                        BF16* __restrict__ out, int ldo, size_t zstride, int nkt) {
  __shared__ __align__(16) BF16 la[128 * 64];
  __shared__ __align__(16) BF16 lb[128 * 64];
  int e = 0, r0;
  const int c0 = blockIdx.x * 128;
  if (GROUPED) {
    int2 d = desc[blockIdx.y];
    if (d.x < 0) return;
    e = d.x;
    r0 = d.y;
  } else {
    r0 = blockIdx.y * 128;
  }
  const int lane = threadIdx.x & 63, wave = threadIdx.x >> 6;
  const int wr = wave >> 1, wc = wave & 1;
  const int k0 = blockIdx.z * nkt * 64;
  const BF16* Ar = A + (size_t)r0 * lda + k0;
  const BF16* Br = B + (size_t)(GROUPED ? e * eB + c0 : c0) * ldb + k0;
  out += (size_t)blockIdx.z * zstride;

  int tok[4];
  if (INDIR) {
#pragma unroll
    for (int j = 0; j < 4; ++j) {
      int t = row_token[r0 + wave * 32 + j * 8 + (lane >> 3)];
      tok[j] = t < 0 ? 0 : t;
    }
  }

  floatx4 acc[4][4] = {};

  for (int kt = 0; kt < nkt; ++kt) {
    if (INDIR)
      stage128x64_indir(A + k0, tok, kt * 64, la, wave, lane);
    else
      stage128x64(Ar + kt * 64, la, lda, wave, lane);
    stage128x64(Br + kt * 64, lb, ldb, wave, lane);
    __syncthreads();
#pragma unroll
    for (int kh = 0; kh < 2; ++kh) {
      short8 af[4], bf[4];
#pragma unroll
      for (int mi = 0; mi < 4; ++mi)
        af[mi] = frag64(la, wr * 64 + mi * 16 + (lane & 15), kh, lane);
#pragma unroll
      for (int ni = 0; ni < 4; ++ni)
        bf[ni] = frag64(lb, wc * 64 + ni * 16 + (lane & 15), kh, lane);
#pragma unroll
      for (int mi = 0; mi < 4; ++mi)
#pragma unroll
        for (int ni = 0; ni < 4; ++ni)
          acc[mi][ni] = __builtin_amdgcn_mfma_f32_16x16x32_bf16(af[mi], bf[ni], acc[mi][ni], 0, 0, 0);
    }
    __syncthreads();
  }

  // Epilogue. C/D layout: col=lane&15, row=(lane>>4)*4+j [m89-verified]
  float rw[4][4];
  if (EPI == 2) {
#pragma unroll
    for (int mi = 0; mi < 4; ++mi)
#pragma unroll
      for (int j = 0; j < 4; ++j)
        rw[mi][j] = row_w[r0 + wr * 64 + mi * 16 + (lane >> 4) * 4 + j];
  }
#pragma unroll
  for (int mi = 0; mi < 4; ++mi)
#pragma unroll
    for (int ni = 0; ni < 4; ++ni)
#pragma unroll
      for (int j = 0; j < 4; ++j) {
        int r = r0 + wr * 64 + mi * 16 + (lane >> 4) * 4 + j;
        int c = c0 + wc * 64 + ni * 16 + (lane & 15);
        float v = acc[mi][ni][j];
        if (EPI >= 1) {
          float g = __bfloat162float(G[(size_t)r * ldo + c]);
          v = gelu_tanh(g) * v;
        }
        if (EPI == 2) v *= rw[mi][j];
        out[(size_t)r * ldo + c] = __float2bfloat16(v);
      }
}

// ---------------------------------------------------------------------------
// Router: rmsnorm stats, xr (w_pre2, bf16), logits, softmax, top-2.
// NO global atomics (counts come from moe_hist).
// ---------------------------------------------------------------------------
__global__ void router_kernel(const float* __restrict__ residual,
                              const float* __restrict__ w_pre2,
                              const float* __restrict__ router_scale,
                              const float* __restrict__ per_expert_scale,
                              const float* __restrict__ Wr,  // [1024][8]
                              BF16* __restrict__ xr,         // [4096][1024]
                              int* __restrict__ top_i, float* __restrict__ top_w) {
  const int lane = threadIdx.x & 63, wave = threadIdx.x >> 6;
  const int n = blockIdx.x * 4 + wave;
  const float* res = residual + (size_t)n * 1024;

  float v[16];
  float ss = 0.f;
#pragma unroll
  for (int i = 0; i < 16; ++i) {
    v[i] = res[lane + i * 64];
    ss += v[i] * v[i];
  }
#pragma unroll
  for (int off = 32; off; off >>= 1) ss += __shfl_xor(ss, off);
  const float inv = rsqrtf(ss * (1.f / 1024.f) + 1e-6f);

  float logits[8] = {};
#pragma unroll
  for (int i = 0; i < 16; ++i) {
    int h = lane + i * 64;
    float nv = v[i] * inv;
    xr[(size_t)n * 1024 + h] = __float2bfloat16(nv * w_pre2[h]);
    float yv = nv * router_scale[h];
#pragma unroll
    for (int ex = 0; ex < 8; ++ex) logits[ex] += yv * Wr[h * 8 + ex];
  }
#pragma unroll
  for (int ex = 0; ex < 8; ++ex)
#pragma unroll
    for (int off = 32; off; off >>= 1) logits[ex] += __shfl_xor(logits[ex], off);

  if (lane == 0) {
    const float hscale = 0.03125f;  // 1024^-0.5
    float mx = -1e30f;
#pragma unroll
    for (int ex = 0; ex < 8; ++ex) {
      logits[ex] *= hscale;
      mx = fmaxf(mx, logits[ex]);
    }
    float p[8];
#pragma unroll
    for (int ex = 0; ex < 8; ++ex) p[ex] = __expf(logits[ex] - mx);
    int i0 = 0;
#pragma unroll
    for (int ex = 1; ex < 8; ++ex)
      if (p[ex] > p[i0]) i0 = ex;
    int i1 = -1;
#pragma unroll
    for (int ex = 0; ex < 8; ++ex)
      if (ex != i0 && (i1 < 0 || p[ex] > p[i1])) i1 = ex;
    float w0 = p[i0], w1 = p[i1];
    float swv = w0 + w1;
    w0 = w0 / swv * per_expert_scale[i0];
    w1 = w1 / swv * per_expert_scale[i1];
    top_i[n * 2] = i0;
    top_i[n * 2 + 1] = i1;
    top_w[n * 2] = w0;
    top_w[n * 2 + 1] = w1;
  }
}

// Per-block LDS histogram of top_i: 32 blocks x 256 threads, 1 pair each.
__global__ void moe_hist(const int* __restrict__ top_i, int* __restrict__ block_hist) {
  __shared__ int h[8];
  if (threadIdx.x < 8) h[threadIdx.x] = 0;
  __syncthreads();
  atomicAdd(&h[top_i[blockIdx.x * 256 + threadIdx.x]], 1);  // LDS atomic
  __syncthreads();
  if (threadIdx.x < 8) block_hist[blockIdx.x * 8 + threadIdx.x] = h[threadIdx.x];
}

// Single block: counts, 128-aligned offsets, tile desc (<=71 of 72, tail=-1),
// per-block bases; init row_token/row_w for all 9216 padded rows.
__global__ void moe_scan(const int* __restrict__ block_hist, int* __restrict__ offsets,
                         int2* __restrict__ desc, int* __restrict__ block_base,
                         int* __restrict__ row_token, float* __restrict__ row_w) {
  if (threadIdx.x == 0) {
    int acc = 0, t = 0;
    for (int e = 0; e < 8; ++e) {
      int cnt = 0;
      for (int b = 0; b < 32; ++b) cnt += block_hist[b * 8 + e];
      offsets[e] = acc;
      int run = acc;
      for (int b = 0; b < 32; ++b) {
        block_base[b * 8 + e] = run;
        run += block_hist[b * 8 + e];
      }
      int ntile = (cnt + 127) >> 7;
      for (int k = 0; k < ntile; ++k) desc[t++] = make_int2(e, acc + k * 128);
      acc += ntile * 128;
    }
    for (; t < 72; ++t) desc[t] = make_int2(-1, 0);
  }
  for (int i = threadIdx.x; i < 9216; i += blockDim.x) {
    row_token[i] = -1;
    row_w[i] = 0.f;
  }
}

// Assign via LDS rank + per-block base. Zero global atomics; output invariant
// to intra-block rank order (rows only permute within an expert segment).
__global__ void moe_assign(const int* __restrict__ top_i, const float* __restrict__ top_w,
                           const int* __restrict__ block_base,
                           int* __restrict__ row_token, float* __restrict__ row_w,
                           int* __restrict__ pair_pos) {
  __shared__ int cur[8];
  if (threadIdx.x < 8) cur[threadIdx.x] = 0;
  __syncthreads();
  const int p = blockIdx.x * 256 + threadIdx.x;
  const int e = top_i[p];
  const int rank = atomicAdd(&cur[e], 1);  // LDS atomic
  const int pos = block_base[blockIdx.x * 8 + e] + rank;
  row_token[pos] = p >> 1;
  row_w[pos] = top_w[p];
  pair_pos[p] = pos;
}

// ---------------------------------------------------------------------------
// Finalize: dense = dp0+dp1 (split-K partials); routed = down_e[p0]+down_e[p1]
// out = rmsnorm(dense)*w_post1 + rmsnorm(routed)*w_post2
// ---------------------------------------------------------------------------
__global__ void finalize_kernel(const BF16* __restrict__ dp0, const BF16* __restrict__ dp1,
                                const BF16* __restrict__ de,
                                const int* __restrict__ pair_pos,
                                const float* __restrict__ w1, const float* __restrict__ w2,
                                float* __restrict__ out) {
  const int n = blockIdx.x, t = threadIdx.x;
  const int p0 = pair_pos[n * 2], p1 = pair_pos[n * 2 + 1];
  float d[4], r[4];
  float ssd = 0.f, ssr = 0.f;
#pragma unroll
  for (int i = 0; i < 4; ++i) {
    int h = t + i * 256;
    d[i] = __bfloat162float(dp0[(size_t)n * 1024 + h]) +
           __bfloat162float(dp1[(size_t)n * 1024 + h]);
    r[i] = __bfloat162float(de[(size_t)p0 * 1024 + h]) +
           __bfloat162float(de[(size_t)p1 * 1024 + h]);
    ssd += d[i] * d[i];
    ssr += r[i] * r[i];
  }
#pragma unroll
  for (int off = 32; off; off >>= 1) {
    ssd += __shfl_xor(ssd, off);
    ssr += __shfl_xor(ssr, off);
  }
  __shared__ float sd[4], sr[4];
  int wave = t >> 6, lane = t & 63;
  if (lane == 0) {
    sd[wave] = ssd;
    sr[wave] = ssr;
  }
  __syncthreads();
  ssd = sd[0] + sd[1] + sd[2] + sd[3];
  ssr = sr[0] + sr[1] + sr[2] + sr[3];
  const float invd = rsqrtf(ssd * (1.f / 1024.f) + 1e-6f);
  const float invr = rsqrtf(ssr * (1.f / 1024.f) + 1e-6f);
#pragma unroll
  for (int i = 0; i < 4; ++i) {
    int h = t + i * 256;
    out[(size_t)n * 1024 + h] = d[i] * invd * w1[h] + r[i] * invr * w2[h];
  }
}

// ---------------------------------------------------------------------------
__global__ void transpose_cvt(const float* __restrict__ in, BF16* __restrict__ out,
                              int rows, int cols) {
  __shared__ float tile[32][33];
  const size_t boff = (size_t)blockIdx.z * rows * cols;
  in += boff;
  out += boff;
  const int c0 = blockIdx.x * 32, r0 = blockIdx.y * 32;
#pragma unroll
  for (int i = 0; i < 4; ++i)
    tile[threadIdx.y + i * 8][threadIdx.x] =
        in[(size_t)(r0 + threadIdx.y + i * 8) * cols + c0 + threadIdx.x];
  __syncthreads();
#pragma unroll
  for (int i = 0; i < 4; ++i)
    out[(size_t)(c0 + threadIdx.y + i * 8) * rows + r0 + threadIdx.x] =
        __float2bfloat16(tile[threadIdx.x][threadIdx.y + i * 8]);
}

__global__ void cvt_bf16_kernel(const float* __restrict__ in, BF16* __restrict__ out) {
  const size_t i = ((size_t)blockIdx.x * blockDim.x + threadIdx.x) * 4;
  float4 v = *(const float4*)(in + i);
  BF16 o[4] = {__float2bfloat16(v.x), __float2bfloat16(v.y),
               __float2bfloat16(v.z), __float2bfloat16(v.w)};
  *(uint2*)(out + i) = *(const uint2*)o;
}

// ---------------------------------------------------------------------------
// Workspace (MiB offsets; lifetime-checked aliasing):
//   0.. 8  x_b      [prepass -> dense-U];   0..18.9 down_e [expert-down -> fin]
//   8..16  xr_b     [router -> expert-U]
//  16..24  WgdT     [prepass -> dense-G]
//  24..32  WudT     [prepass -> dense-U]
//  32..40  WddT     [prepass -> dense-down]
//  40..48  WgeT     [prepass -> expert-G];  40..56 dp01 [dense-down -> fin]
//  48..56  WueT     [prepass -> expert-U]
//  56..64  WdeT_e   [prepass -> expert-down]
//  64..96  HBUF     [dense-U -> dense-down]
//  96..128 Gbuf     [dense-G -> dense-U]; then S bookkeeping (96..96.2) +
//  97..106 G_e      [expert-G -> expert-U]
// 106..115 HBUF_e   [expert-U -> expert-down]
// ---------------------------------------------------------------------------
extern "C" void kernel_launch(void* const* d_in, const int* in_sizes, int n_in,
                              void* d_out, int out_size, void* d_ws, size_t ws_size,
                              hipStream_t stream) {
  const float* x = (const float*)d_in[0];
  const float* res = (const float*)d_in[1];
  const float* Wg_d = (const float*)d_in[2];
  const float* Wu_d = (const float*)d_in[3];
  const float* Wd_d = (const float*)d_in[4];
  const float* w_post1 = (const float*)d_in[5];
  const float* w_pre2 = (const float*)d_in[6];
  const float* w_post2 = (const float*)d_in[7];
  const float* router_scale = (const float*)d_in[8];
  const float* per_expert_scale = (const float*)d_in[9];
  const float* Wr = (const float*)d_in[10];
  const float* Wg_e = (const float*)d_in[11];
  const float* Wu_e = (const float*)d_in[12];
  const float* Wd_e = (const float*)d_in[13];
  float* out = (float*)d_out;

  char* ws = (char*)d_ws;
  const size_t MB = 1ull << 20;
  BF16* x_b = (BF16*)(ws + 0 * MB);
  BF16* down_e = (BF16*)(ws + 0 * MB);
  BF16* xr_b = (BF16*)(ws + 8 * MB);
  BF16* WgdT = (BF16*)(ws + 16 * MB);
  BF16* WudT = (BF16*)(ws + 24 * MB);
  BF16* WddT = (BF16*)(ws + 32 * MB);
  BF16* WgeT = (BF16*)(ws + 40 * MB);
  BF16* dp01 = (BF16*)(ws + 40 * MB);
  BF16* WueT = (BF16*)(ws + 48 * MB);
  BF16* WdeT_e = (BF16*)(ws + 56 * MB);
  BF16* HBUF = (BF16*)(ws + 64 * MB);
  BF16* Gbuf = (BF16*)(ws + 96 * MB);
  BF16* G_e = (BF16*)(ws + 97 * MB);
  BF16* HBUF_e = (BF16*)(ws + 106 * MB);
  char* S = ws + 96 * MB;  // bookkeeping, lives after Gbuf is dead
  int* top_i = (int*)(S);                    // [8192]
  float* top_w = (float*)(S + 32 * 1024);    // [8192]
  int* pair_pos = (int*)(S + 64 * 1024);     // [8192]
  int* row_token = (int*)(S + 96 * 1024);    // [9216]
  float* row_w = (float*)(S + 136 * 1024);   // [9216]
  int* offsets = (int*)(S + 176 * 1024);     // [8]
  int2* desc = (int2*)(S + 177 * 1024);      // [72]
  int* block_hist = (int*)(S + 180 * 1024);  // [32][8]
  int* block_base = (int*)(S + 184 * 1024);  // [32][8]

  dim3 tb(32, 8);
  // pre-pass: conversions + weight transposes (B^T layout, bf16)
  cvt_bf16_kernel<<<4096, 256, 0, stream>>>(x, x_b);
  transpose_cvt<<<dim3(128, 32, 1), tb, 0, stream>>>(Wg_d, WgdT, 1024, 4096);
  transpose_cvt<<<dim3(128, 32, 1), tb, 0, stream>>>(Wu_d, WudT, 1024, 4096);
  transpose_cvt<<<dim3(32, 128, 1), tb, 0, stream>>>(Wd_d, WddT, 4096, 1024);
  transpose_cvt<<<dim3(16, 32, 8), tb, 0, stream>>>(Wg_e, WgeT, 1024, 512);
  transpose_cvt<<<dim3(16, 32, 8), tb, 0, stream>>>(Wu_e, WueT, 1024, 512);
  transpose_cvt<<<dim3(32, 16, 8), tb, 0, stream>>>(Wd_e, WdeT_e, 512, 1024);

  // dense path part 1: G = x@Wg ; HBUF = gelu(G) * (x@Wu)
  gemm_bt<0, 0, 0><<<dim3(32, 32, 1), 256, 0, stream>>>(
      x_b, 1024, WgdT, 1024, 0, nullptr, nullptr, nullptr, nullptr, Gbuf, 4096, 0, 16);
  gemm_bt<1, 0, 0><<<dim3(32, 32, 1), 256, 0, stream>>>(
      x_b, 1024, WudT, 1024, 0, nullptr, nullptr, Gbuf, nullptr, HBUF, 4096, 0, 16);

  // router + MoE bookkeeping (zero global atomics)
  router_kernel<<<1024, 256, 0, stream>>>(res, w_pre2, router_scale, per_expert_scale,
                                          Wr, xr_b, top_i, top_w);
  moe_hist<<<32, 256, 0, stream>>>(top_i, block_hist);
  moe_scan<<<1, 256, 0, stream>>>(block_hist, offsets, desc, block_base, row_token,
                                  row_w);
  moe_assign<<<32, 256, 0, stream>>>(top_i, top_w, block_base, row_token, row_w,
                                     pair_pos);

  // expert path: G_e = xr@Wg_e ; HBUF_e = gelu(G_e)*(xr@Wu_e)*row_w ; down
  gemm_bt<0, 1, 1><<<dim3(4, 72, 1), 256, 0, stream>>>(
      xr_b, 1024, WgeT, 1024, 512, desc, row_token, nullptr, nullptr, G_e, 512, 0, 16);
  gemm_bt<2, 1, 1><<<dim3(4, 72, 1), 256, 0, stream>>>(
      xr_b, 1024, WueT, 1024, 512, desc, row_token, G_e, row_w, HBUF_e, 512, 0, 16);
  gemm_bt<0, 0, 1><<<dim3(8, 72, 1), 256, 0, stream>>>(
      HBUF_e, 512, WdeT_e, 512, 1024, desc, nullptr, nullptr, nullptr, down_e, 1024, 0, 8);

  // dense down: split-K=2, bf16 partials over dead WgeT/WueT space
  gemm_bt<0, 0, 0><<<dim3(8, 32, 2), 256, 0, stream>>>(
      HBUF, 4096, WddT, 4096, 0, nullptr, nullptr, nullptr, nullptr, dp01, 1024,
      (size_t)4096 * 1024, 32);

  // out = rmsnorm(dense)*w_post1 + rmsnorm(routed)*w_post2
  finalize_kernel<<<4096, 256, 0, stream>>>(dp01, dp01 + (size_t)4096 * 1024, down_e,
                                            pair_pos, w_post1, w_post2, out);
}